// Round 3
// baseline (32984.000 us; speedup 1.0000x reference)
//
#include <hip/hip_runtime.h>
#include <math.h>

// Problem constants
#define B_ 64
#define T_ 512
#define D_ 1024
#define H_ 1024
#define G4 4096          // 4*H
#define EPS 1e-5f
#define KS 8             // K-split for per-step hh GEMM

// ---------------------------------------------------------------------------
// Workspace layouts (floats)
// Path A (big ws): precomputed input gates
#define H2_OFF 0                                   // h[2][B][H]
#define C2_OFF (2 * B_ * H_)                       // c[2][B][H]
#define PP_OFF (4 * B_ * H_)                       // pp[KS][2][B][4H]
#define GIH_OFF (PP_OFF + KS * 2 * B_ * G4)        // gih[2][T*B][4H] (post-LN), row = t*64+b
#define WS_NEED_A ((size_t)(GIH_OFF + 2ULL * T_ * B_ * G4) * 4ULL)

// Path B (fallback, small ws; round-1 layout)
#define AIH_OFF 0
#define AHH_OFF (2 * B_ * G4)
#define H_OFF   (4 * B_ * G4)
#define C_OFF   (H_OFF + 2 * B_ * H_)

__device__ __forceinline__ float sigmoidf_(float x) {
    return 1.0f / (1.0f + expf(-x));
}

// ===========================================================================
// PATH A kernels
// ===========================================================================

// init h/c state
__global__ __launch_bounds__(256)
void lstm_init2(float* __restrict__ ws,
                const float* __restrict__ fwd_init,
                const float* __restrict__ bwd_init) {
    int idx = blockIdx.x * 256 + threadIdx.x;   // [2][64][1024]
    int dir = idx >> 16;
    int k = idx & (H_ - 1);
    const float* init = dir ? bwd_init : fwd_init;   // [2,H]: row0=h0, row1=c0
    ws[H2_OFF + idx] = init[k];
    ws[C2_OFF + idx] = init[H_ + k];
}

// ---------------------------------------------------------------------------
// Batched input GEMM: for dir in {f,b}: gih[dir][t*64+b][:] = x[b][t'] . W^T + bias
// (t' = T-1-t for dir=1, time-reversed input; outputs NOT re-flipped — faithful).
// x is [B,T,D] (row (b,t) at x + (b*T+t)*D).
// M = T*B = 32768 per dir, N = 4096, K = 1024.
// Tile 128x128, BK=16, 256 threads, 8x8 per thread.
// grid = 2 * 256 * 32 = 16384
#define SA128 132   // LDS row stride (floats): %4==0 for float4, non-pow2 for banks
__global__ __launch_bounds__(256)
void gemm128(const float* __restrict__ x,
             const float* __restrict__ wf, const float* __restrict__ bf,
             const float* __restrict__ wb, const float* __restrict__ bb,
             float* __restrict__ gih) {
    const int bid = blockIdx.x;
    const int dir = bid >> 13;
    const int mt = (bid >> 5) & 255;
    const int nt = bid & 31;
    const float* W = dir ? wb : wf;
    const float* bias = dir ? bb : bf;

    __shared__ __align__(16) float Ash[16 * SA128];
    __shared__ __align__(16) float Bsh[16 * SA128];

    const int tid = threadIdx.x;
    const int tx = tid & 15;      // col group: cols tx*8 .. +8
    const int ty = tid >> 4;      // row group: rows ty*8 .. +8

    // staging: thread stages tile rows r0 (t-local 0) and r0+64 (t-local 1), k-quad kq
    const int r0 = tid >> 2;      // 0..63 == batch index b
    const int kq = tid & 3;
    // tile rows 0..63  <-> (t = 2*mt,   b = r0)
    // tile rows 64..127<-> (t = 2*mt+1, b = r0)
    const int t0 = 2 * mt;
    const int t1 = 2 * mt + 1;
    const int t0s = dir ? (T_ - 1 - t0) : t0;
    const int t1s = dir ? (T_ - 1 - t1) : t1;
    const float* ap0 = x + ((size_t)r0 * T_ + t0s) * D_ + kq * 4;   // x is [B,T,D]
    const float* ap1 = x + ((size_t)r0 * T_ + t1s) * D_ + kq * 4;
    const float* bp0 = W + (size_t)(nt * 128 + r0) * D_ + kq * 4;
    const float* bp1 = W + (size_t)(nt * 128 + r0 + 64) * D_ + kq * 4;

    float acc[8][8] = {{0.f}};

    for (int kb = 0; kb < 1024; kb += 16) {
        float4 a0 = *(const float4*)(ap0 + kb);
        float4 a1 = *(const float4*)(ap1 + kb);
        float4 b0 = *(const float4*)(bp0 + kb);
        float4 b1 = *(const float4*)(bp1 + kb);
        #pragma unroll
        for (int w = 0; w < 4; ++w) {
            Ash[(kq * 4 + w) * SA128 + r0]      = ((const float*)&a0)[w];
            Ash[(kq * 4 + w) * SA128 + r0 + 64] = ((const float*)&a1)[w];
            Bsh[(kq * 4 + w) * SA128 + r0]      = ((const float*)&b0)[w];
            Bsh[(kq * 4 + w) * SA128 + r0 + 64] = ((const float*)&b1)[w];
        }
        __syncthreads();

        #pragma unroll
        for (int kk = 0; kk < 16; ++kk) {
            float4 av0 = *(const float4*)&Ash[kk * SA128 + ty * 8];
            float4 av1 = *(const float4*)&Ash[kk * SA128 + ty * 8 + 4];
            float4 bv0 = *(const float4*)&Bsh[kk * SA128 + tx * 8];
            float4 bv1 = *(const float4*)&Bsh[kk * SA128 + tx * 8 + 4];
            float ar[8] = {av0.x, av0.y, av0.z, av0.w, av1.x, av1.y, av1.z, av1.w};
            float br[8] = {bv0.x, bv0.y, bv0.z, bv0.w, bv1.x, bv1.y, bv1.z, bv1.w};
            #pragma unroll
            for (int i = 0; i < 8; ++i)
                #pragma unroll
                for (int j = 0; j < 8; ++j)
                    acc[i][j] = fmaf(ar[i], br[j], acc[i][j]);
        }
        __syncthreads();
    }

    // epilogue: + bias, store pre-LN (row composite R = t*64+b matches update2)
    const int c0 = nt * 128 + tx * 8;
    float4 bs0 = *(const float4*)&bias[c0];
    float4 bs1 = *(const float4*)&bias[c0 + 4];
    #pragma unroll
    for (int i = 0; i < 8; ++i) {
        int R = mt * 128 + ty * 8 + i;
        float* op = gih + ((size_t)dir * (T_ * B_) + R) * G4 + c0;
        float4 o0, o1;
        o0.x = acc[i][0] + bs0.x; o0.y = acc[i][1] + bs0.y;
        o0.z = acc[i][2] + bs0.z; o0.w = acc[i][3] + bs0.w;
        o1.x = acc[i][4] + bs1.x; o1.y = acc[i][5] + bs1.y;
        o1.z = acc[i][6] + bs1.z; o1.w = acc[i][7] + bs1.w;
        *(float4*)op = o0;
        *(float4*)(op + 4) = o1;
    }
}

// ---------------------------------------------------------------------------
// In-place LN over each 4096 row of gih. grid = 2*T*B = 65536 blocks.
__global__ __launch_bounds__(256)
void ln_rows(float* __restrict__ gih,
             const float* __restrict__ gf, const float* __restrict__ bef,
             const float* __restrict__ gb, const float* __restrict__ beb) {
    const int row = blockIdx.x;
    const int dir = row >> 15;           // T*B = 32768
    float* p = gih + (size_t)row * G4;
    const float* g  = dir ? gb  : gf;
    const float* be = dir ? beb : bef;

    const int tid = threadIdx.x;
    float4 v[4];
    float s1 = 0.f, s2 = 0.f;
    #pragma unroll
    for (int q = 0; q < 4; ++q) {
        v[q] = *(const float4*)&p[tid * 16 + q * 4];
        s1 += v[q].x + v[q].y + v[q].z + v[q].w;
        s2 += v[q].x * v[q].x + v[q].y * v[q].y + v[q].z * v[q].z + v[q].w * v[q].w;
    }
    __shared__ float red[4][2];
    __shared__ float st[2];
    int lane = tid & 63, wv = tid >> 6;
    #pragma unroll
    for (int off = 32; off > 0; off >>= 1) {
        s1 += __shfl_down(s1, off);
        s2 += __shfl_down(s2, off);
    }
    if (lane == 0) { red[wv][0] = s1; red[wv][1] = s2; }
    __syncthreads();
    if (tid == 0) {
        float a = red[0][0] + red[1][0] + red[2][0] + red[3][0];
        float b = red[0][1] + red[1][1] + red[2][1] + red[3][1];
        float mu = a / (float)G4;
        float var = b / (float)G4 - mu * mu;
        st[0] = mu; st[1] = rsqrtf(var + EPS);
    }
    __syncthreads();
    const float mu = st[0], rs = st[1];
    #pragma unroll
    for (int q = 0; q < 4; ++q) {
        int c = tid * 16 + q * 4;
        float4 gg = *(const float4*)&g[c];
        float4 bb = *(const float4*)&be[c];
        float4 o;
        o.x = (v[q].x - mu) * rs * gg.x + bb.x;
        o.y = (v[q].y - mu) * rs * gg.y + bb.y;
        o.z = (v[q].z - mu) * rs * gg.z + bb.z;
        o.w = (v[q].w - mu) * rs * gg.w + bb.w;
        *(float4*)&p[c] = o;
    }
}

// ---------------------------------------------------------------------------
// Per-step hidden GEMM partials:
//   pp[ks][dir][b][j] = sum_{k in chunk ks} h[dir][b][k] * Whh[j][k]
// Tile 64(M) x 256(N), K-chunk 128 (BK=16), 256 threads, 8x8 per thread.
// grid = 2 * 16 * KS = 256
#define SAH 68
#define SBH 260
__global__ __launch_bounds__(256)
void gemm_hh(const float* __restrict__ whhf, const float* __restrict__ whhb,
             float* __restrict__ ws) {
    const int bid = blockIdx.x;
    const int dir = bid >> 7;
    const int nt = (bid >> 3) & 15;
    const int ks = bid & 7;
    const float* W = dir ? whhb : whhf;
    const float* A = ws + H2_OFF + (size_t)dir * (B_ * H_);
    float* outp = ws + PP_OFF + ((size_t)ks * 2 + dir) * (B_ * G4);

    __shared__ __align__(16) float Ash[16 * SAH];
    __shared__ __align__(16) float Bsh[16 * SBH];

    const int tid = threadIdx.x;
    const int tx = tid & 31;      // col group: cols tx*8 (of 256)
    const int ty = tid >> 5;      // row group: rows ty*8 (of 64)

    const int r0 = tid >> 2;      // A-stage row 0..63
    const int kq = tid & 3;
    const int k0 = ks * 128;

    const float* ap = A + (size_t)r0 * H_ + k0 + kq * 4;
    const float* bp = W + (size_t)(nt * 256 + r0) * H_ + k0 + kq * 4;

    float acc[8][8] = {{0.f}};

    for (int kb = 0; kb < 128; kb += 16) {
        float4 av = *(const float4*)(ap + kb);
        #pragma unroll
        for (int w = 0; w < 4; ++w)
            Ash[(kq * 4 + w) * SAH + r0] = ((const float*)&av)[w];
        #pragma unroll
        for (int j = 0; j < 4; ++j) {
            float4 bv = *(const float4*)(bp + (size_t)j * 64 * H_ + kb);
            #pragma unroll
            for (int w = 0; w < 4; ++w)
                Bsh[(kq * 4 + w) * SBH + r0 + j * 64] = ((const float*)&bv)[w];
        }
        __syncthreads();

        #pragma unroll
        for (int kk = 0; kk < 16; ++kk) {
            float4 av0 = *(const float4*)&Ash[kk * SAH + ty * 8];
            float4 av1 = *(const float4*)&Ash[kk * SAH + ty * 8 + 4];
            float4 bv0 = *(const float4*)&Bsh[kk * SBH + tx * 8];
            float4 bv1 = *(const float4*)&Bsh[kk * SBH + tx * 8 + 4];
            float ar[8] = {av0.x, av0.y, av0.z, av0.w, av1.x, av1.y, av1.z, av1.w};
            float br[8] = {bv0.x, bv0.y, bv0.z, bv0.w, bv1.x, bv1.y, bv1.z, bv1.w};
            #pragma unroll
            for (int i = 0; i < 8; ++i)
                #pragma unroll
                for (int j = 0; j < 8; ++j)
                    acc[i][j] = fmaf(ar[i], br[j], acc[i][j]);
        }
        __syncthreads();
    }

    const int c0 = nt * 256 + tx * 8;
    #pragma unroll
    for (int i = 0; i < 8; ++i) {
        float* op = outp + (size_t)(ty * 8 + i) * G4 + c0;
        float4 o0 = {acc[i][0], acc[i][1], acc[i][2], acc[i][3]};
        float4 o1 = {acc[i][4], acc[i][5], acc[i][6], acc[i][7]};
        *(float4*)op = o0;
        *(float4*)(op + 4) = o1;
    }
}

// ---------------------------------------------------------------------------
// Per-step: sum partials + bias -> LN -> + gih -> gates -> c,h update -> out
// grid = 128 (dir*64+b), 256 threads
__global__ __launch_bounds__(256)
void lstm_update2(float* __restrict__ ws,
                  const float* __restrict__ bhhf, const float* __restrict__ ghhf,
                  const float* __restrict__ behhf,
                  const float* __restrict__ bhhb, const float* __restrict__ ghhb,
                  const float* __restrict__ behhb,
                  float* __restrict__ out, int s) {
    const int dir = blockIdx.x >> 6;
    const int b = blockIdx.x & 63;
    const float* bhh  = dir ? bhhb  : bhhf;
    const float* ghh  = dir ? ghhb  : ghhf;
    const float* behh = dir ? behhb : behhf;

    const int tid = threadIdx.x;
    __shared__ __align__(16) float srow[G4];
    __shared__ float red[4][2];
    __shared__ float st[2];

    // phase 1: sum partials + bias over this thread's 16 cols; stats
    float4 v[4];
    float s1 = 0.f, s2 = 0.f;
    #pragma unroll
    for (int q = 0; q < 4; ++q) {
        int c = tid * 16 + q * 4;
        float4 acc = *(const float4*)&bhh[c];
        #pragma unroll
        for (int ks = 0; ks < KS; ++ks) {
            const float4 p = *(const float4*)&ws[PP_OFF + (((size_t)ks * 2 + dir) * B_ + b) * G4 + c];
            acc.x += p.x; acc.y += p.y; acc.z += p.z; acc.w += p.w;
        }
        v[q] = acc;
        s1 += acc.x + acc.y + acc.z + acc.w;
        s2 += acc.x * acc.x + acc.y * acc.y + acc.z * acc.z + acc.w * acc.w;
    }
    int lane = tid & 63, wv = tid >> 6;
    #pragma unroll
    for (int off = 32; off > 0; off >>= 1) {
        s1 += __shfl_down(s1, off);
        s2 += __shfl_down(s2, off);
    }
    if (lane == 0) { red[wv][0] = s1; red[wv][1] = s2; }
    __syncthreads();
    if (tid == 0) {
        float a = red[0][0] + red[1][0] + red[2][0] + red[3][0];
        float bq = red[0][1] + red[1][1] + red[2][1] + red[3][1];
        float mu = a / (float)G4;
        float var = bq / (float)G4 - mu * mu;
        st[0] = mu; st[1] = rsqrtf(var + EPS);
    }
    __syncthreads();
    const float mu = st[0], rs = st[1];

    // gih row for this step: R = s*64 + b
    const float* gi_row = ws + GIH_OFF + ((size_t)dir * (T_ * B_) + (size_t)s * B_ + b) * G4;
    #pragma unroll
    for (int q = 0; q < 4; ++q) {
        int c = tid * 16 + q * 4;
        float4 gg = *(const float4*)&ghh[c];
        float4 bb = *(const float4*)&behh[c];
        float4 gi = *(const float4*)&gi_row[c];
        float4 o;
        o.x = (v[q].x - mu) * rs * gg.x + bb.x + gi.x;
        o.y = (v[q].y - mu) * rs * gg.y + bb.y + gi.y;
        o.z = (v[q].z - mu) * rs * gg.z + bb.z + gi.z;
        o.w = (v[q].w - mu) * rs * gg.w + bb.w + gi.w;
        *(float4*)&srow[c] = o;
    }
    __syncthreads();

    // phase 2: gates at k, k+1024, k+2048, k+3072 (i,f,g,o order)
    float* hrow = ws + H2_OFF + ((size_t)dir * B_ + b) * H_;
    float* crow = ws + C2_OFF + ((size_t)dir * B_ + b) * H_;
    const int k0 = tid * 4;
    float4 gi_ = *(const float4*)&srow[k0];
    float4 gf_ = *(const float4*)&srow[1024 + k0];
    float4 gg_ = *(const float4*)&srow[2048 + k0];
    float4 go_ = *(const float4*)&srow[3072 + k0];
    float4 cv = *(const float4*)&crow[k0];
    float4 cn, hn;
    cn.x = sigmoidf_(gf_.x) * cv.x + sigmoidf_(gi_.x) * tanhf(gg_.x);
    cn.y = sigmoidf_(gf_.y) * cv.y + sigmoidf_(gi_.y) * tanhf(gg_.y);
    cn.z = sigmoidf_(gf_.z) * cv.z + sigmoidf_(gi_.z) * tanhf(gg_.z);
    cn.w = sigmoidf_(gf_.w) * cv.w + sigmoidf_(gi_.w) * tanhf(gg_.w);
    hn.x = sigmoidf_(go_.x) * tanhf(cn.x);
    hn.y = sigmoidf_(go_.y) * tanhf(cn.y);
    hn.z = sigmoidf_(go_.z) * tanhf(cn.z);
    hn.w = sigmoidf_(go_.w) * tanhf(cn.w);
    *(float4*)&crow[k0] = cn;
    *(float4*)&hrow[k0] = hn;
    *(float4*)&out[((size_t)b * T_ + s) * (2 * H_) + dir * H_ + k0] = hn;
    if (s == T_ - 1) {
        *(float4*)&out[(size_t)B_ * T_ * (2 * H_) + (size_t)b * (2 * H_) + dir * H_ + k0] = hn;
    }
}

// ===========================================================================
// PATH B kernels (small-ws fallback; recompute input gates per step)
// ===========================================================================

__global__ __launch_bounds__(256)
void lstm_init(float* __restrict__ ws,
               const float* __restrict__ fwd_init,
               const float* __restrict__ bwd_init) {
    int idx = blockIdx.x * 256 + threadIdx.x;
    int dir = idx >> 16;
    int k = idx & (H_ - 1);
    const float* init = dir ? bwd_init : fwd_init;
    ws[H_OFF + idx] = init[k];
    ws[C_OFF + idx] = init[H_ + k];
}

__global__ __launch_bounds__(256)
void lstm_gemm4(const float* __restrict__ x,
                const float* __restrict__ wihf, const float* __restrict__ whhf,
                const float* __restrict__ wihb, const float* __restrict__ whhb,
                const float* __restrict__ bihf, const float* __restrict__ bhhf,
                const float* __restrict__ bihb, const float* __restrict__ bhhb,
                float* __restrict__ ws, int s) {
    const int g = blockIdx.x >> 6;
    const int tile = blockIdx.x & 63;
    const float* Abase;
    size_t Astride;
    const float* W;
    const float* bias;
    float* outp;
    switch (g) {
        case 0: Abase = x + (size_t)s * D_;              Astride = (size_t)T_ * D_;
                W = wihf; bias = bihf; outp = ws + AIH_OFF;                      break;
        case 1: Abase = ws + H_OFF;                      Astride = H_;
                W = whhf; bias = bhhf; outp = ws + AHH_OFF;                      break;
        case 2: Abase = x + (size_t)(T_ - 1 - s) * D_;   Astride = (size_t)T_ * D_;
                W = wihb; bias = bihb; outp = ws + AIH_OFF + (size_t)B_ * G4;    break;
        default: Abase = ws + H_OFF + (size_t)B_ * H_;   Astride = H_;
                W = whhb; bias = bhhb; outp = ws + AHH_OFF + (size_t)B_ * G4;    break;
    }

    __shared__ __align__(16) float Ash[32 * 68];
    __shared__ __align__(16) float Bsh[32 * 68];

    const int tid = threadIdx.x;
    const int tx = tid & 15;
    const int ty = tid >> 4;
    const int c0g = tile * 64;

    float acc[4][4] = {{0.f}};

    for (int kb = 0; kb < 1024; kb += 32) {
        #pragma unroll
        for (int l = 0; l < 2; ++l) {
            int q = tid + l * 256;
            int r = q >> 3;
            int kq = q & 7;
            float4 av = *(const float4*)(Abase + (size_t)r * Astride + kb + kq * 4);
            float4 bv = *(const float4*)(W + (size_t)(c0g + r) * 1024 + kb + kq * 4);
            #pragma unroll
            for (int w = 0; w < 4; ++w) {
                Ash[(kq * 4 + w) * 68 + r] = ((const float*)&av)[w];
                Bsh[(kq * 4 + w) * 68 + r] = ((const float*)&bv)[w];
            }
        }
        __syncthreads();

        #pragma unroll
        for (int kk = 0; kk < 32; ++kk) {
            float4 a = *(const float4*)&Ash[kk * 68 + ty * 4];
            float4 b = *(const float4*)&Bsh[kk * 68 + tx * 4];
            #pragma unroll
            for (int i = 0; i < 4; ++i) {
                float ai = ((const float*)&a)[i];
                #pragma unroll
                for (int j = 0; j < 4; ++j) {
                    acc[i][j] = fmaf(ai, ((const float*)&b)[j], acc[i][j]);
                }
            }
        }
        __syncthreads();
    }

    float4 bs = *(const float4*)&bias[c0g + tx * 4];
    #pragma unroll
    for (int i = 0; i < 4; ++i) {
        float4 o;
        o.x = acc[i][0] + bs.x;
        o.y = acc[i][1] + bs.y;
        o.z = acc[i][2] + bs.z;
        o.w = acc[i][3] + bs.w;
        *(float4*)&outp[(size_t)(ty * 4 + i) * G4 + c0g + tx * 4] = o;
    }
}

__global__ __launch_bounds__(256)
void lstm_update(float* __restrict__ ws,
                 const float* __restrict__ gihf, const float* __restrict__ beihf,
                 const float* __restrict__ ghhf, const float* __restrict__ behhf,
                 const float* __restrict__ gihb, const float* __restrict__ beihb,
                 const float* __restrict__ ghhb, const float* __restrict__ behhb,
                 float* __restrict__ out, int s) {
    const int dir = blockIdx.x >> 6;
    const int b = blockIdx.x & 63;

    const float* aih = ws + AIH_OFF + ((size_t)dir * B_ + b) * G4;
    const float* ahh = ws + AHH_OFF + ((size_t)dir * B_ + b) * G4;
    const float* gih  = dir ? gihb  : gihf;
    const float* beih = dir ? beihb : beihf;
    const float* ghh  = dir ? ghhb  : ghhf;
    const float* behh = dir ? behhb : behhf;

    float si = 0.f, ssi = 0.f, sh = 0.f, ssh = 0.f;
    for (int t = threadIdx.x; t < G4; t += 256) {
        float v = aih[t]; si += v; ssi += v * v;
        float u = ahh[t]; sh += u; ssh += u * u;
    }
    __shared__ float red[4][4];
    __shared__ float stats[4];
    int lane = threadIdx.x & 63, w = threadIdx.x >> 6;
    #pragma unroll
    for (int off = 32; off > 0; off >>= 1) {
        si  += __shfl_down(si, off);
        ssi += __shfl_down(ssi, off);
        sh  += __shfl_down(sh, off);
        ssh += __shfl_down(ssh, off);
    }
    if (lane == 0) { red[w][0] = si; red[w][1] = ssi; red[w][2] = sh; red[w][3] = ssh; }
    __syncthreads();
    if (threadIdx.x == 0) {
        float a = 0.f, bq = 0.f, cq = 0.f, dq = 0.f;
        #pragma unroll
        for (int i = 0; i < 4; ++i) { a += red[i][0]; bq += red[i][1]; cq += red[i][2]; dq += red[i][3]; }
        float mui = a / (float)G4;
        float vari = bq / (float)G4 - mui * mui;
        float muh = cq / (float)G4;
        float varh = dq / (float)G4 - muh * muh;
        stats[0] = mui; stats[1] = rsqrtf(vari + EPS);
        stats[2] = muh; stats[3] = rsqrtf(varh + EPS);
    }
    __syncthreads();
    const float mui = stats[0], rsi = stats[1], muh = stats[2], rsh = stats[3];

    float* hrow = ws + H_OFF + ((size_t)dir * B_ + b) * H_;
    float* crow = ws + C_OFF + ((size_t)dir * B_ + b) * H_;

    for (int k = threadIdx.x; k < H_; k += 256) {
        float gates[4];
        #pragma unroll
        for (int q = 0; q < 4; ++q) {
            int j = q * 1024 + k;
            float gi = (aih[j] - mui) * rsi * gih[j] + beih[j];
            float gh = (ahh[j] - muh) * rsh * ghh[j] + behh[j];
            gates[q] = gi + gh;
        }
        float ig = sigmoidf_(gates[0]);
        float fg = sigmoidf_(gates[1]);
        float gg = tanhf(gates[2]);
        float og = sigmoidf_(gates[3]);
        float cn = fg * crow[k] + ig * gg;
        float hn = og * tanhf(cn);
        crow[k] = cn;
        hrow[k] = hn;
        out[((size_t)b * T_ + s) * (2 * H_) + dir * H_ + k] = hn;
        if (s == T_ - 1) {
            out[(size_t)B_ * T_ * (2 * H_) + (size_t)b * (2 * H_) + dir * H_ + k] = hn;
        }
    }
}

// ---------------------------------------------------------------------------
extern "C" void kernel_launch(void* const* d_in, const int* in_sizes, int n_in,
                              void* d_out, int out_size, void* d_ws, size_t ws_size,
                              hipStream_t stream) {
    const float* x     = (const float*)d_in[0];
    const float* wihf  = (const float*)d_in[1];
    const float* whhf  = (const float*)d_in[2];
    const float* bihf  = (const float*)d_in[3];
    const float* bhhf  = (const float*)d_in[4];
    const float* gihf  = (const float*)d_in[5];
    const float* beihf = (const float*)d_in[6];
    const float* ghhf  = (const float*)d_in[7];
    const float* behhf = (const float*)d_in[8];
    const float* wihb  = (const float*)d_in[9];
    const float* whhb  = (const float*)d_in[10];
    const float* bihb  = (const float*)d_in[11];
    const float* bhhb  = (const float*)d_in[12];
    const float* gihb  = (const float*)d_in[13];
    const float* beihb = (const float*)d_in[14];
    const float* ghhb  = (const float*)d_in[15];
    const float* behhb = (const float*)d_in[16];
    const float* fwd_init = (const float*)d_in[17];
    const float* bwd_init = (const float*)d_in[18];

    float* ws  = (float*)d_ws;
    float* out = (float*)d_out;

    if (ws_size >= WS_NEED_A) {
        // Path A: precompute input gates, hh-only recurrence
        hipLaunchKernelGGL(lstm_init2, dim3(512), dim3(256), 0, stream, ws, fwd_init, bwd_init);
        hipLaunchKernelGGL(gemm128, dim3(16384), dim3(256), 0, stream,
                           x, wihf, bihf, wihb, bihb, ws + GIH_OFF);
        hipLaunchKernelGGL(ln_rows, dim3(2 * T_ * B_), dim3(256), 0, stream,
                           ws + GIH_OFF, gihf, beihf, gihb, beihb);
        for (int s = 0; s < T_; ++s) {
            hipLaunchKernelGGL(gemm_hh, dim3(256), dim3(256), 0, stream, whhf, whhb, ws);
            hipLaunchKernelGGL(lstm_update2, dim3(128), dim3(256), 0, stream,
                               ws, bhhf, ghhf, behhf, bhhb, ghhb, behhb, out, s);
        }
    } else {
        // Path B: small-ws fallback
        hipLaunchKernelGGL(lstm_init, dim3(512), dim3(256), 0, stream, ws, fwd_init, bwd_init);
        for (int s = 0; s < T_; ++s) {
            hipLaunchKernelGGL(lstm_gemm4, dim3(256), dim3(256), 0, stream,
                               x, wihf, whhf, wihb, whhb,
                               bihf, bhhf, bihb, bhhb, ws, s);
            hipLaunchKernelGGL(lstm_update, dim3(128), dim3(256), 0, stream,
                               ws, gihf, beihf, ghhf, behhf,
                               gihb, beihb, ghhb, behhb, out, s);
        }
    }
}

// Round 5
// 25163.036 us; speedup vs baseline: 1.3108x; 1.3108x over previous
//
#include <hip/hip_runtime.h>
#include <math.h>

// Problem constants
#define B_ 64
#define T_ 512
#define D_ 1024
#define H_ 1024
#define G4 4096          // 4*H
#define EPS 1e-5f
#define KS 8             // K-split for per-step hh GEMM

// ---------------------------------------------------------------------------
// Workspace layout, Path C (floats); chunk buffer size chosen at runtime.
#define H2_OFF 0                                   // h[2][B][H]
#define C2_OFF (2 * B_ * H_)                       // c[2][B][H]
#define PP_OFF (4 * B_ * H_)                       // pp[KS][2][B][4H]
#define GC_OFF (PP_OFF + KS * 2 * B_ * G4)         // gch[2][ch*B][4H] post-LN, row = tl*64+b

// Path B (fallback, small ws)
#define AIH_OFF 0
#define AHH_OFF (2 * B_ * G4)
#define H_OFF   (4 * B_ * G4)
#define C_OFF   (H_OFF + 2 * B_ * H_)

__device__ __forceinline__ float sigmoidf_(float x) {
    return 1.0f / (1.0f + expf(-x));
}

// ===========================================================================
// PATH C kernels
// ===========================================================================

// init h/c state
__global__ __launch_bounds__(256)
void lstm_init2(float* __restrict__ ws,
                const float* __restrict__ fwd_init,
                const float* __restrict__ bwd_init) {
    int idx = blockIdx.x * 256 + threadIdx.x;   // [2][64][1024]
    int dir = idx >> 16;
    int k = idx & (H_ - 1);
    const float* init = dir ? bwd_init : fwd_init;   // [2,H]: row0=h0, row1=c0
    ws[H2_OFF + idx] = init[k];
    ws[C2_OFF + idx] = init[H_ + k];
}

// ---------------------------------------------------------------------------
// Chunked input GEMM: for dir, for steps s0..s0+ch-1:
//   gch[dir][(t-s0)*64+b][:] = x[b][t'] . W^T + bias,  t' = dir ? T-1-t : t
// x is [B,T,D]. Per chunk: M = ch*B rows per dir, N = 4096, K = 1024.
// Tile 128x128, BK=16, 256 threads, 8x8 per thread.
// grid = 2 * mtmax * 32 where mtmax = ch/2.
#define SA128 132   // LDS row stride (floats): %4==0 for float4, non-pow2 for banks
__global__ __launch_bounds__(256)
void gemm128c(const float* __restrict__ x,
              const float* __restrict__ wf, const float* __restrict__ bf,
              const float* __restrict__ wb, const float* __restrict__ bb,
              float* __restrict__ gch, int s0, int mtmax, int chB) {
    const int bid = blockIdx.x;
    const int per_dir = mtmax * 32;
    const int dir = bid / per_dir;
    const int within = bid - dir * per_dir;
    const int mt = within >> 5;
    const int nt = within & 31;
    const float* W = dir ? wb : wf;
    const float* bias = dir ? bb : bf;

    __shared__ __align__(16) float Ash[16 * SA128];
    __shared__ __align__(16) float Bsh[16 * SA128];

    const int tid = threadIdx.x;
    const int tx = tid & 15;      // col group: cols tx*8 .. +8
    const int ty = tid >> 4;      // row group: rows ty*8 .. +8

    // staging: thread stages tile rows r0 (t-local even) and r0+64 (odd), k-quad kq
    const int r0 = tid >> 2;      // 0..63 == batch index b
    const int kq = tid & 3;
    // tile rows 0..63   <-> (t = s0 + 2*mt,     b = r0)
    // tile rows 64..127 <-> (t = s0 + 2*mt + 1, b = r0)
    const int t0 = s0 + 2 * mt;
    const int t1 = t0 + 1;
    const int t0s = dir ? (T_ - 1 - t0) : t0;
    const int t1s = dir ? (T_ - 1 - t1) : t1;
    const float* ap0 = x + ((size_t)r0 * T_ + t0s) * D_ + kq * 4;   // x is [B,T,D]
    const float* ap1 = x + ((size_t)r0 * T_ + t1s) * D_ + kq * 4;
    const float* bp0 = W + (size_t)(nt * 128 + r0) * D_ + kq * 4;
    const float* bp1 = W + (size_t)(nt * 128 + r0 + 64) * D_ + kq * 4;

    float acc[8][8] = {{0.f}};

    for (int kb = 0; kb < 1024; kb += 16) {
        float4 a0 = *(const float4*)(ap0 + kb);
        float4 a1 = *(const float4*)(ap1 + kb);
        float4 b0 = *(const float4*)(bp0 + kb);
        float4 b1 = *(const float4*)(bp1 + kb);
        #pragma unroll
        for (int w = 0; w < 4; ++w) {
            Ash[(kq * 4 + w) * SA128 + r0]      = ((const float*)&a0)[w];
            Ash[(kq * 4 + w) * SA128 + r0 + 64] = ((const float*)&a1)[w];
            Bsh[(kq * 4 + w) * SA128 + r0]      = ((const float*)&b0)[w];
            Bsh[(kq * 4 + w) * SA128 + r0 + 64] = ((const float*)&b1)[w];
        }
        __syncthreads();

        #pragma unroll
        for (int kk = 0; kk < 16; ++kk) {
            float4 av0 = *(const float4*)&Ash[kk * SA128 + ty * 8];
            float4 av1 = *(const float4*)&Ash[kk * SA128 + ty * 8 + 4];
            float4 bv0 = *(const float4*)&Bsh[kk * SA128 + tx * 8];
            float4 bv1 = *(const float4*)&Bsh[kk * SA128 + tx * 8 + 4];
            float ar[8] = {av0.x, av0.y, av0.z, av0.w, av1.x, av1.y, av1.z, av1.w};
            float br[8] = {bv0.x, bv0.y, bv0.z, bv0.w, bv1.x, bv1.y, bv1.z, bv1.w};
            #pragma unroll
            for (int i = 0; i < 8; ++i)
                #pragma unroll
                for (int j = 0; j < 8; ++j)
                    acc[i][j] = fmaf(ar[i], br[j], acc[i][j]);
        }
        __syncthreads();
    }

    // epilogue: + bias, store pre-LN into chunk buffer (row = tl*64 + b)
    const int c0 = nt * 128 + tx * 8;
    float4 bs0 = *(const float4*)&bias[c0];
    float4 bs1 = *(const float4*)&bias[c0 + 4];
    #pragma unroll
    for (int i = 0; i < 8; ++i) {
        int R = mt * 128 + ty * 8 + i;                 // local row (tl*64 + b)
        float* op = gch + ((size_t)dir * chB + R) * G4 + c0;
        float4 o0, o1;
        o0.x = acc[i][0] + bs0.x; o0.y = acc[i][1] + bs0.y;
        o0.z = acc[i][2] + bs0.z; o0.w = acc[i][3] + bs0.w;
        o1.x = acc[i][4] + bs1.x; o1.y = acc[i][5] + bs1.y;
        o1.z = acc[i][6] + bs1.z; o1.w = acc[i][7] + bs1.w;
        *(float4*)op = o0;
        *(float4*)(op + 4) = o1;
    }
}

// ---------------------------------------------------------------------------
// In-place LN over each 4096 row of the chunk buffer. grid = 2*ch*B.
__global__ __launch_bounds__(256)
void ln_rowsc(float* __restrict__ gch,
              const float* __restrict__ gf, const float* __restrict__ bef,
              const float* __restrict__ gb, const float* __restrict__ beb,
              int chB) {
    const int row = blockIdx.x;
    const int dir = row / chB;
    float* p = gch + (size_t)row * G4;
    const float* g  = dir ? gb  : gf;
    const float* be = dir ? beb : bef;

    const int tid = threadIdx.x;
    float4 v[4];
    float s1 = 0.f, s2 = 0.f;
    #pragma unroll
    for (int q = 0; q < 4; ++q) {
        v[q] = *(const float4*)&p[tid * 16 + q * 4];
        s1 += v[q].x + v[q].y + v[q].z + v[q].w;
        s2 += v[q].x * v[q].x + v[q].y * v[q].y + v[q].z * v[q].z + v[q].w * v[q].w;
    }
    __shared__ float red[4][2];
    __shared__ float st[2];
    int lane = tid & 63, wv = tid >> 6;
    #pragma unroll
    for (int off = 32; off > 0; off >>= 1) {
        s1 += __shfl_down(s1, off);
        s2 += __shfl_down(s2, off);
    }
    if (lane == 0) { red[wv][0] = s1; red[wv][1] = s2; }
    __syncthreads();
    if (tid == 0) {
        float a = red[0][0] + red[1][0] + red[2][0] + red[3][0];
        float b = red[0][1] + red[1][1] + red[2][1] + red[3][1];
        float mu = a / (float)G4;
        float var = b / (float)G4 - mu * mu;
        st[0] = mu; st[1] = rsqrtf(var + EPS);
    }
    __syncthreads();
    const float mu = st[0], rs = st[1];
    #pragma unroll
    for (int q = 0; q < 4; ++q) {
        int c = tid * 16 + q * 4;
        float4 gg = *(const float4*)&g[c];
        float4 bb = *(const float4*)&be[c];
        float4 o;
        o.x = (v[q].x - mu) * rs * gg.x + bb.x;
        o.y = (v[q].y - mu) * rs * gg.y + bb.y;
        o.z = (v[q].z - mu) * rs * gg.z + bb.z;
        o.w = (v[q].w - mu) * rs * gg.w + bb.w;
        *(float4*)&p[c] = o;
    }
}

// ---------------------------------------------------------------------------
// Per-step hidden GEMM partials:
//   pp[ks][dir][b][j] = sum_{k in chunk ks} h[dir][b][k] * Whh[j][k]
// Tile 64(M) x 256(N), K-chunk 128 (BK=16), 256 threads, 8x8 per thread.
// grid = 2 * 16 * KS = 256
#define SAH 68
#define SBH 260
__global__ __launch_bounds__(256)
void gemm_hh4(const float* __restrict__ whhf, const float* __restrict__ whhb,
              float* __restrict__ ws) {
    const int bid = blockIdx.x;
    const int dir = bid >> 7;
    const int nt = (bid >> 3) & 15;
    const int ks = bid & 7;
    const float* W = dir ? whhb : whhf;
    const float* A = ws + H2_OFF + (size_t)dir * (B_ * H_);
    float* outp = ws + PP_OFF + ((size_t)ks * 2 + dir) * (B_ * G4);

    __shared__ __align__(16) float Ash[16 * SAH];
    __shared__ __align__(16) float Bsh[16 * SBH];

    const int tid = threadIdx.x;
    const int tx = tid & 31;      // col group: cols tx*8 (of 256)
    const int ty = tid >> 5;      // row group: rows ty*8 (of 64)

    const int r0 = tid >> 2;      // A-stage row 0..63
    const int kq = tid & 3;
    const int k0 = ks * 128;

    const float* ap = A + (size_t)r0 * H_ + k0 + kq * 4;
    const float* bp = W + (size_t)(nt * 256 + r0) * H_ + k0 + kq * 4;

    float acc[8][8] = {{0.f}};

    for (int kb = 0; kb < 128; kb += 16) {
        float4 av = *(const float4*)(ap + kb);
        #pragma unroll
        for (int w = 0; w < 4; ++w)
            Ash[(kq * 4 + w) * SAH + r0] = ((const float*)&av)[w];
        #pragma unroll
        for (int j = 0; j < 4; ++j) {
            float4 bv = *(const float4*)(bp + (size_t)j * 64 * H_ + kb);
            #pragma unroll
            for (int w = 0; w < 4; ++w)
                Bsh[(kq * 4 + w) * SBH + r0 + j * 64] = ((const float*)&bv)[w];
        }
        __syncthreads();

        #pragma unroll
        for (int kk = 0; kk < 16; ++kk) {
            float4 av0 = *(const float4*)&Ash[kk * SAH + ty * 8];
            float4 av1 = *(const float4*)&Ash[kk * SAH + ty * 8 + 4];
            float4 bv0 = *(const float4*)&Bsh[kk * SBH + tx * 8];
            float4 bv1 = *(const float4*)&Bsh[kk * SBH + tx * 8 + 4];
            float ar[8] = {av0.x, av0.y, av0.z, av0.w, av1.x, av1.y, av1.z, av1.w};
            float br[8] = {bv0.x, bv0.y, bv0.z, bv0.w, bv1.x, bv1.y, bv1.z, bv1.w};
            #pragma unroll
            for (int i = 0; i < 8; ++i)
                #pragma unroll
                for (int j = 0; j < 8; ++j)
                    acc[i][j] = fmaf(ar[i], br[j], acc[i][j]);
        }
        __syncthreads();
    }

    const int c0 = nt * 256 + tx * 8;
    #pragma unroll
    for (int i = 0; i < 8; ++i) {
        float* op = outp + (size_t)(ty * 8 + i) * G4 + c0;
        float4 o0 = {acc[i][0], acc[i][1], acc[i][2], acc[i][3]};
        float4 o1 = {acc[i][4], acc[i][5], acc[i][6], acc[i][7]};
        *(float4*)op = o0;
        *(float4*)(op + 4) = o1;
    }
}

// ---------------------------------------------------------------------------
// Per-step: sum partials + bias -> LN -> + gih(chunk) -> gates -> c,h -> out
// grid = 128 (dir*64+b), 256 threads
__global__ __launch_bounds__(256)
void lstm_update2(float* __restrict__ ws,
                  const float* __restrict__ bhhf, const float* __restrict__ ghhf,
                  const float* __restrict__ behhf,
                  const float* __restrict__ bhhb, const float* __restrict__ ghhb,
                  const float* __restrict__ behhb,
                  float* __restrict__ out, int s, int sl, int chB) {
    const int dir = blockIdx.x >> 6;
    const int b = blockIdx.x & 63;
    const float* bhh  = dir ? bhhb  : bhhf;
    const float* ghh  = dir ? ghhb  : ghhf;
    const float* behh = dir ? behhb : behhf;

    const int tid = threadIdx.x;
    __shared__ __align__(16) float srow[G4];
    __shared__ float red[4][2];
    __shared__ float st[2];

    // phase 1: sum partials + bias over this thread's 16 cols; stats
    float4 v[4];
    float s1 = 0.f, s2 = 0.f;
    #pragma unroll
    for (int q = 0; q < 4; ++q) {
        int c = tid * 16 + q * 4;
        float4 acc = *(const float4*)&bhh[c];
        #pragma unroll
        for (int ks = 0; ks < KS; ++ks) {
            const float4 p = *(const float4*)&ws[PP_OFF + (((size_t)ks * 2 + dir) * B_ + b) * G4 + c];
            acc.x += p.x; acc.y += p.y; acc.z += p.z; acc.w += p.w;
        }
        v[q] = acc;
        s1 += acc.x + acc.y + acc.z + acc.w;
        s2 += acc.x * acc.x + acc.y * acc.y + acc.z * acc.z + acc.w * acc.w;
    }
    int lane = tid & 63, wv = tid >> 6;
    #pragma unroll
    for (int off = 32; off > 0; off >>= 1) {
        s1 += __shfl_down(s1, off);
        s2 += __shfl_down(s2, off);
    }
    if (lane == 0) { red[wv][0] = s1; red[wv][1] = s2; }
    __syncthreads();
    if (tid == 0) {
        float a = red[0][0] + red[1][0] + red[2][0] + red[3][0];
        float bq = red[0][1] + red[1][1] + red[2][1] + red[3][1];
        float mu = a / (float)G4;
        float var = bq / (float)G4 - mu * mu;
        st[0] = mu; st[1] = rsqrtf(var + EPS);
    }
    __syncthreads();
    const float mu = st[0], rs = st[1];

    // input-gate row from chunk buffer: local row = sl*64 + b
    const float* gi_row = ws + GC_OFF + ((size_t)dir * chB + (size_t)sl * B_ + b) * G4;
    #pragma unroll
    for (int q = 0; q < 4; ++q) {
        int c = tid * 16 + q * 4;
        float4 gg = *(const float4*)&ghh[c];
        float4 bb = *(const float4*)&behh[c];
        float4 gi = *(const float4*)&gi_row[c];
        float4 o;
        o.x = (v[q].x - mu) * rs * gg.x + bb.x + gi.x;
        o.y = (v[q].y - mu) * rs * gg.y + bb.y + gi.y;
        o.z = (v[q].z - mu) * rs * gg.z + bb.z + gi.z;
        o.w = (v[q].w - mu) * rs * gg.w + bb.w + gi.w;
        *(float4*)&srow[c] = o;
    }
    __syncthreads();

    // phase 2: gates at k, k+1024, k+2048, k+3072 (i,f,g,o order)
    float* hrow = ws + H2_OFF + ((size_t)dir * B_ + b) * H_;
    float* crow = ws + C2_OFF + ((size_t)dir * B_ + b) * H_;
    const int k0 = tid * 4;
    float4 gi_ = *(const float4*)&srow[k0];
    float4 gf_ = *(const float4*)&srow[1024 + k0];
    float4 gg_ = *(const float4*)&srow[2048 + k0];
    float4 go_ = *(const float4*)&srow[3072 + k0];
    float4 cv = *(const float4*)&crow[k0];
    float4 cn, hn;
    cn.x = sigmoidf_(gf_.x) * cv.x + sigmoidf_(gi_.x) * tanhf(gg_.x);
    cn.y = sigmoidf_(gf_.y) * cv.y + sigmoidf_(gi_.y) * tanhf(gg_.y);
    cn.z = sigmoidf_(gf_.z) * cv.z + sigmoidf_(gi_.z) * tanhf(gg_.z);
    cn.w = sigmoidf_(gf_.w) * cv.w + sigmoidf_(gi_.w) * tanhf(gg_.w);
    hn.x = sigmoidf_(go_.x) * tanhf(cn.x);
    hn.y = sigmoidf_(go_.y) * tanhf(cn.y);
    hn.z = sigmoidf_(go_.z) * tanhf(cn.z);
    hn.w = sigmoidf_(go_.w) * tanhf(cn.w);
    *(float4*)&crow[k0] = cn;
    *(float4*)&hrow[k0] = hn;
    *(float4*)&out[((size_t)b * T_ + s) * (2 * H_) + dir * H_ + k0] = hn;
    if (s == T_ - 1) {
        *(float4*)&out[(size_t)B_ * T_ * (2 * H_) + (size_t)b * (2 * H_) + dir * H_ + k0] = hn;
    }
}

// ===========================================================================
// PATH B kernels (small-ws fallback; recompute input gates per step)
// ===========================================================================

__global__ __launch_bounds__(256)
void lstm_init(float* __restrict__ ws,
               const float* __restrict__ fwd_init,
               const float* __restrict__ bwd_init) {
    int idx = blockIdx.x * 256 + threadIdx.x;
    int dir = idx >> 16;
    int k = idx & (H_ - 1);
    const float* init = dir ? bwd_init : fwd_init;
    ws[H_OFF + idx] = init[k];
    ws[C_OFF + idx] = init[H_ + k];
}

__global__ __launch_bounds__(256)
void lstm_gemm4(const float* __restrict__ x,
                const float* __restrict__ wihf, const float* __restrict__ whhf,
                const float* __restrict__ wihb, const float* __restrict__ whhb,
                const float* __restrict__ bihf, const float* __restrict__ bhhf,
                const float* __restrict__ bihb, const float* __restrict__ bhhb,
                float* __restrict__ ws, int s) {
    const int g = blockIdx.x >> 6;
    const int tile = blockIdx.x & 63;
    const float* Abase;
    size_t Astride;
    const float* W;
    const float* bias;
    float* outp;
    switch (g) {
        case 0: Abase = x + (size_t)s * D_;              Astride = (size_t)T_ * D_;
                W = wihf; bias = bihf; outp = ws + AIH_OFF;                      break;
        case 1: Abase = ws + H_OFF;                      Astride = H_;
                W = whhf; bias = bhhf; outp = ws + AHH_OFF;                      break;
        case 2: Abase = x + (size_t)(T_ - 1 - s) * D_;   Astride = (size_t)T_ * D_;
                W = wihb; bias = bihb; outp = ws + AIH_OFF + (size_t)B_ * G4;    break;
        default: Abase = ws + H_OFF + (size_t)B_ * H_;   Astride = H_;
                W = whhb; bias = bhhb; outp = ws + AHH_OFF + (size_t)B_ * G4;    break;
    }

    __shared__ __align__(16) float Ash[32 * 68];
    __shared__ __align__(16) float Bsh[32 * 68];

    const int tid = threadIdx.x;
    const int tx = tid & 15;
    const int ty = tid >> 4;
    const int c0g = tile * 64;

    float acc[4][4] = {{0.f}};

    for (int kb = 0; kb < 1024; kb += 32) {
        #pragma unroll
        for (int l = 0; l < 2; ++l) {
            int q = tid + l * 256;
            int r = q >> 3;
            int kq = q & 7;
            float4 av = *(const float4*)(Abase + (size_t)r * Astride + kb + kq * 4);
            float4 bv = *(const float4*)(W + (size_t)(c0g + r) * 1024 + kb + kq * 4);
            #pragma unroll
            for (int w = 0; w < 4; ++w) {
                Ash[(kq * 4 + w) * 68 + r] = ((const float*)&av)[w];
                Bsh[(kq * 4 + w) * 68 + r] = ((const float*)&bv)[w];
            }
        }
        __syncthreads();

        #pragma unroll
        for (int kk = 0; kk < 32; ++kk) {
            float4 a = *(const float4*)&Ash[kk * 68 + ty * 4];
            float4 b = *(const float4*)&Bsh[kk * 68 + tx * 4];
            #pragma unroll
            for (int i = 0; i < 4; ++i) {
                float ai = ((const float*)&a)[i];
                #pragma unroll
                for (int j = 0; j < 4; ++j) {
                    acc[i][j] = fmaf(ai, ((const float*)&b)[j], acc[i][j]);
                }
            }
        }
        __syncthreads();
    }

    float4 bs = *(const float4*)&bias[c0g + tx * 4];
    #pragma unroll
    for (int i = 0; i < 4; ++i) {
        float4 o;
        o.x = acc[i][0] + bs.x;
        o.y = acc[i][1] + bs.y;
        o.z = acc[i][2] + bs.z;
        o.w = acc[i][3] + bs.w;
        *(float4*)&outp[(size_t)(ty * 4 + i) * G4 + c0g + tx * 4] = o;
    }
}

__global__ __launch_bounds__(256)
void lstm_update(float* __restrict__ ws,
                 const float* __restrict__ gihf, const float* __restrict__ beihf,
                 const float* __restrict__ ghhf, const float* __restrict__ behhf,
                 const float* __restrict__ gihb, const float* __restrict__ beihb,
                 const float* __restrict__ ghhb, const float* __restrict__ behhb,
                 float* __restrict__ out, int s) {
    const int dir = blockIdx.x >> 6;
    const int b = blockIdx.x & 63;

    const float* aih = ws + AIH_OFF + ((size_t)dir * B_ + b) * G4;
    const float* ahh = ws + AHH_OFF + ((size_t)dir * B_ + b) * G4;
    const float* gih  = dir ? gihb  : gihf;
    const float* beih = dir ? beihb : beihf;
    const float* ghh  = dir ? ghhb  : ghhf;
    const float* behh = dir ? behhb : behhf;

    float si = 0.f, ssi = 0.f, sh = 0.f, ssh = 0.f;
    for (int t = threadIdx.x; t < G4; t += 256) {
        float v = aih[t]; si += v; ssi += v * v;
        float u = ahh[t]; sh += u; ssh += u * u;
    }
    __shared__ float red[4][4];
    __shared__ float stats[4];
    int lane = threadIdx.x & 63, w = threadIdx.x >> 6;
    #pragma unroll
    for (int off = 32; off > 0; off >>= 1) {
        si  += __shfl_down(si, off);
        ssi += __shfl_down(ssi, off);
        sh  += __shfl_down(sh, off);
        ssh += __shfl_down(ssh, off);
    }
    if (lane == 0) { red[w][0] = si; red[w][1] = ssi; red[w][2] = sh; red[w][3] = ssh; }
    __syncthreads();
    if (threadIdx.x == 0) {
        float a = 0.f, bq = 0.f, cq = 0.f, dq = 0.f;
        #pragma unroll
        for (int i = 0; i < 4; ++i) { a += red[i][0]; bq += red[i][1]; cq += red[i][2]; dq += red[i][3]; }
        float mui = a / (float)G4;
        float vari = bq / (float)G4 - mui * mui;
        float muh = cq / (float)G4;
        float varh = dq / (float)G4 - muh * muh;
        stats[0] = mui; stats[1] = rsqrtf(vari + EPS);
        stats[2] = muh; stats[3] = rsqrtf(varh + EPS);
    }
    __syncthreads();
    const float mui = stats[0], rsi = stats[1], muh = stats[2], rsh = stats[3];

    float* hrow = ws + H_OFF + ((size_t)dir * B_ + b) * H_;
    float* crow = ws + C_OFF + ((size_t)dir * B_ + b) * H_;

    for (int k = threadIdx.x; k < H_; k += 256) {
        float gates[4];
        #pragma unroll
        for (int q = 0; q < 4; ++q) {
            int j = q * 1024 + k;
            float gi = (aih[j] - mui) * rsi * gih[j] + beih[j];
            float gh = (ahh[j] - muh) * rsh * ghh[j] + behh[j];
            gates[q] = gi + gh;
        }
        float ig = sigmoidf_(gates[0]);
        float fg = sigmoidf_(gates[1]);
        float gg = tanhf(gates[2]);
        float og = sigmoidf_(gates[3]);
        float cn = fg * crow[k] + ig * gg;
        float hn = og * tanhf(cn);
        crow[k] = cn;
        hrow[k] = hn;
        out[((size_t)b * T_ + s) * (2 * H_) + dir * H_ + k] = hn;
        if (s == T_ - 1) {
            out[(size_t)B_ * T_ * (2 * H_) + (size_t)b * (2 * H_) + dir * H_ + k] = hn;
        }
    }
}

// ---------------------------------------------------------------------------
extern "C" void kernel_launch(void* const* d_in, const int* in_sizes, int n_in,
                              void* d_out, int out_size, void* d_ws, size_t ws_size,
                              hipStream_t stream) {
    const float* x     = (const float*)d_in[0];
    const float* wihf  = (const float*)d_in[1];
    const float* whhf  = (const float*)d_in[2];
    const float* bihf  = (const float*)d_in[3];
    const float* bhhf  = (const float*)d_in[4];
    const float* gihf  = (const float*)d_in[5];
    const float* beihf = (const float*)d_in[6];
    const float* ghhf  = (const float*)d_in[7];
    const float* behhf = (const float*)d_in[8];
    const float* wihb  = (const float*)d_in[9];
    const float* whhb  = (const float*)d_in[10];
    const float* bihb  = (const float*)d_in[11];
    const float* bihb2 = (const float*)d_in[12];   // b_hh_b
    const float* gihb  = (const float*)d_in[13];
    const float* beihb = (const float*)d_in[14];
    const float* ghhb  = (const float*)d_in[15];
    const float* behhb = (const float*)d_in[16];
    const float* fwd_init = (const float*)d_in[17];
    const float* bwd_init = (const float*)d_in[18];
    const float* bhhb = bihb2;

    float* ws  = (float*)d_ws;
    float* out = (float*)d_out;

    // pick largest chunk length that fits in ws
    int ch = 0;
    for (int c = 32; c >= 2; c >>= 1) {
        size_t need = ((size_t)GC_OFF + 2ULL * c * B_ * G4) * 4ULL;
        if (need <= ws_size) { ch = c; break; }
    }

    if (ch >= 2) {
        // Path C: chunked input-gate precompute + hh-only recurrence
        const int chB = ch * B_;
        const int mtmax = ch / 2;
        hipLaunchKernelGGL(lstm_init2, dim3(512), dim3(256), 0, stream, ws, fwd_init, bwd_init);
        const int nch = T_ / ch;
        for (int c = 0; c < nch; ++c) {
            const int s0 = c * ch;
            hipLaunchKernelGGL(gemm128c, dim3(2 * mtmax * 32), dim3(256), 0, stream,
                               x, wihf, bihf, wihb, bihb, ws + GC_OFF, s0, mtmax, chB);
            hipLaunchKernelGGL(ln_rowsc, dim3(2 * chB), dim3(256), 0, stream,
                               ws + GC_OFF, gihf, beihf, gihb, beihb, chB);
            for (int sl = 0; sl < ch; ++sl) {
                hipLaunchKernelGGL(gemm_hh4, dim3(256), dim3(256), 0, stream, whhf, whhb, ws);
                hipLaunchKernelGGL(lstm_update2, dim3(128), dim3(256), 0, stream,
                                   ws, bhhf, ghhf, behhf, bhhb, ghhb, behhb, out, s0 + sl, sl, chB);
            }
        }
    } else {
        // Path B: small-ws fallback
        hipLaunchKernelGGL(lstm_init, dim3(512), dim3(256), 0, stream, ws, fwd_init, bwd_init);
        for (int s = 0; s < T_; ++s) {
            hipLaunchKernelGGL(lstm_gemm4, dim3(256), dim3(256), 0, stream,
                               x, wihf, whhf, wihb, whhb,
                               bihf, bhhf, bihb, bhhb, ws, s);
            hipLaunchKernelGGL(lstm_update, dim3(128), dim3(256), 0, stream,
                               ws, gihf, beihf, ghhf, behhf,
                               gihb, beihb, ghhb, behhb, out, s);
        }
    }
}